// Round 1
// 4611.149 us; speedup vs baseline: 2.2809x; 2.2809x over previous
//
#include <hip/hip_runtime.h>
#include <hip/hip_bf16.h>
#include <math.h>

// Problem constants (fixed by the reference)
#define H_DIM 4096
#define NQ    32
#define NKV   8
#define HD    128
#define GRPQ  4
#define NQKV  6144      // NQ*HD + 2*NKV*HD
#define KOFF  4096      // column offset of K region in qkv
#define VOFF  5120      // column offset of V region in qkv
#define SCALE 0.08838834764831844f   // 128^-0.5

typedef float f32x4 __attribute__((ext_vector_type(4)));
typedef short bf16x8 __attribute__((ext_vector_type(8)));

static __device__ __forceinline__ float bf2f(unsigned short u) {
    return __uint_as_float(((unsigned int)u) << 16);
}
static __device__ __forceinline__ unsigned short f2bf(float f) {
    return __bfloat16_as_ushort(__float2bfloat16(f));
}

// 4-element vector load -> float4, overloaded on source dtype.
static __device__ __forceinline__ float4 load4(const float* p) {
    return *reinterpret_cast<const float4*>(p);
}
static __device__ __forceinline__ float4 load4(const unsigned short* p) {
    ushort4 v = *reinterpret_cast<const ushort4*>(p);
    return make_float4(bf2f(v.x), bf2f(v.y), bf2f(v.z), bf2f(v.w));
}

// Scalar store, overloaded on destination dtype (fp32 or bf16-bits).
static __device__ __forceinline__ void store1(float* p, float v) { *p = v; }
static __device__ __forceinline__ void store1(unsigned short* p, float v) {
    *p = f2bf(v);
}

// ---------------------------------------------------------------------------
// Generic GEMM: C[M,N] = A[M,K] @ B[K,N], row-major, fp32 accumulate.
// (unchanged this round; next target for MFMA conversion)
// ---------------------------------------------------------------------------
#define BM 128
#define BN 128
#define BK 16
#define LPAD 4

template <typename TA, typename TB, typename TC>
__global__ __launch_bounds__(256) void gemm_f32acc(
    const TA* __restrict__ A,
    const TB* __restrict__ B,
    TC* __restrict__ C,
    int M, int N, int K)
{
    __shared__ float As[BK][BM + LPAD];
    __shared__ float Bs[BK][BN + LPAD];

    const int tid = threadIdx.x;
    const int bm  = blockIdx.y * BM;
    const int bn  = blockIdx.x * BN;
    const int tx  = tid & 15;
    const int ty  = tid >> 4;

    float acc[8][8];
#pragma unroll
    for (int i = 0; i < 8; ++i)
#pragma unroll
        for (int j = 0; j < 8; ++j) acc[i][j] = 0.0f;

    for (int k0 = 0; k0 < K; k0 += BK) {
        for (int q = tid; q < (BM * BK) / 4; q += 256) {
            int row = q >> 2;
            int kq  = (q & 3) << 2;
            float4 v = load4(&A[(size_t)(bm + row) * K + k0 + kq]);
            As[kq + 0][row] = v.x;
            As[kq + 1][row] = v.y;
            As[kq + 2][row] = v.z;
            As[kq + 3][row] = v.w;
        }
        for (int q = tid; q < (BK * BN) / 4; q += 256) {
            int k = q >> 5;
            int n = (q & 31) << 2;
            float4 v = load4(&B[(size_t)(k0 + k) * N + bn + n]);
            Bs[k][n + 0] = v.x;
            Bs[k][n + 1] = v.y;
            Bs[k][n + 2] = v.z;
            Bs[k][n + 3] = v.w;
        }
        __syncthreads();

#pragma unroll
        for (int k = 0; k < BK; ++k) {
            float a[8], b[8];
#pragma unroll
            for (int i = 0; i < 8; ++i) a[i] = As[k][ty * 8 + i];
#pragma unroll
            for (int j = 0; j < 8; ++j) b[j] = Bs[k][tx * 8 + j];
#pragma unroll
            for (int i = 0; i < 8; ++i)
#pragma unroll
                for (int j = 0; j < 8; ++j) acc[i][j] += a[i] * b[j];
        }
        __syncthreads();
    }

#pragma unroll
    for (int i = 0; i < 8; ++i) {
        size_t r = (size_t)(bm + ty * 8 + i);
#pragma unroll
        for (int j = 0; j < 8; ++j) {
            int c = bn + tx * 8 + j;
            store1(&C[r * N + c], acc[i][j]);
        }
    }
}

// ---------------------------------------------------------------------------
// RoPE applied in place to the Q and K regions of qkv (S x 6144, bf16).
// ---------------------------------------------------------------------------
__global__ __launch_bounds__(256) void rope_kernel(
    unsigned short* __restrict__ qkv,
    const int* __restrict__ pos32,
    int S)
{
    int idx = blockIdx.x * 256 + threadIdx.x;
    int total = S * (NQ + NKV) * (HD / 2);
    if (idx >= total) return;

    int j    = idx & 63;
    int head = (idx >> 6) % (NQ + NKV);
    int s    = idx / (64 * (NQ + NKV));

    const bool is64 = (pos32[1] == 0);      // int64 little-endian arange
    int pos = is64 ? pos32[2 * s] : pos32[s];

    unsigned short* row = qkv + (size_t)s * NQKV + head * HD;
    float x1 = bf2f(row[j]);
    float x2 = bf2f(row[j + 64]);

    float p = (float)pos;
    float inv_freq = powf(10000.0f, -((float)j) * (1.0f / 64.0f));
    float f = p * inv_freq;
    float sn, cs;
    sincosf(f, &sn, &cs);

    row[j]      = f2bf(x1 * cs - x2 * sn);
    row[j + 64] = f2bf(x2 * cs + x1 * sn);
}

// ---------------------------------------------------------------------------
// MFMA flash attention (bf16 in, fp32 accum, bf16 out).
//
// Block = 256 threads = 4 waves, handles one q-head and 64 q-rows.
// Wave w owns q-rows [s0+16w, s0+16w+16). Per 64-key tile:
//   QK^T : mfma_f32_16x16x32_bf16, A = Q (registers), B = K^T (LDS, swizzled)
//   softmax: wave-parallel, online m/l in registers; P stays in registers
//            laid out exactly as the PV A-fragment.
//   PV   : A = P (regs), B = V^T (LDS, staged transposed + swizzled)
//
// LDS layouts (all 16B-chunk XOR-swizzled: chunk ^= row&7 -> bank-conflict
// free at the b128 wave floor):
//   Ks : 64 rows x 256B  (row = key, chunk = d>>3)
//   Vts: 128 rows x 128B (row = d,   chunk = key>>3)  [transposed V]
//   Ss : per-wave 16 x 68 f32 score tile (C-layout -> softmax transpose)
// ---------------------------------------------------------------------------
__global__ __launch_bounds__(256) void attn_mfma(
    const unsigned short* __restrict__ qkv,   // S x 6144 bf16 bits (RoPE'd)
    unsigned short* __restrict__ attn_out,    // S x 4096 bf16 bits
    int S)
{
    __shared__ unsigned short Ks[64 * 128];    // 16 KB
    __shared__ unsigned short Vts[128 * 64];   // 16 KB
    __shared__ float Ss[4][16 * 68];           // 17 KB (per-wave, 68 = 64+4 pad)

    const int tid  = threadIdx.x;
    const int lane = tid & 63;
    const int w    = tid >> 6;        // wave 0..3
    const int l15  = lane & 15;
    const int l4   = lane >> 4;       // quarter 0..3
    const int h    = blockIdx.y;      // query head
    const int g    = h >> 2;          // kv head
    const int s0   = blockIdx.x * 64;

    // --- Q A-fragments in registers: rows s0+16w+l15, k = ks*32 + l4*8 + i ---
    bf16x8 qf[4];
    {
        const unsigned short* qrow =
            qkv + (size_t)(s0 + w * 16 + l15) * NQKV + h * HD;
#pragma unroll
        for (int ks = 0; ks < 4; ++ks)
            qf[ks] = *reinterpret_cast<const bf16x8*>(qrow + ks * 32 + l4 * 8);
    }

    f32x4 oacc[8];
#pragma unroll
    for (int dt = 0; dt < 8; ++dt) oacc[dt] = (f32x4){0.f, 0.f, 0.f, 0.f};
    float m_r = -1e30f;   // running max for row l15 (replicated over quarters)
    float l_r = 0.0f;     // running denom for row l15

    const int nt = blockIdx.x + 1;    // 64-key tiles (last one is diagonal)
    for (int t = 0; t < nt; ++t) {
        const int t0 = t * 64;
        __syncthreads();   // previous tile's LDS reads done

        // ---- stage K tile: coalesced 16B loads, swizzled b128 LDS writes ----
#pragma unroll
        for (int it = 0; it < 4; ++it) {
            int cc  = tid + it * 256;         // 0..1023 16B chunks
            int key = cc >> 4;
            int c   = cc & 15;                // chunk within 256B row
            bf16x8 v = *reinterpret_cast<const bf16x8*>(
                qkv + (size_t)(t0 + key) * NQKV + KOFF + g * HD + c * 8);
            *reinterpret_cast<bf16x8*>(
                reinterpret_cast<char*>(Ks) + key * 256 + ((c ^ (key & 7)) << 4)) = v;
        }
        // ---- stage V tile TRANSPOSED: per-lane 16B row reads, u16 scatter ----
#pragma unroll
        for (int it = 0; it < 4; ++it) {
            int cc  = tid + it * 256;
            int key = cc & 63;
            int d0  = (cc >> 6) * 8;
            bf16x8 v = *reinterpret_cast<const bf16x8*>(
                qkv + (size_t)(t0 + key) * NQKV + VOFF + g * HD + d0);
#pragma unroll
            for (int j = 0; j < 8; ++j) {
                // Vts[d0+j][key], chunk (key>>3) ^ ((d0+j)&7) = (key>>3)^j
                *reinterpret_cast<unsigned short*>(
                    reinterpret_cast<char*>(Vts) + (d0 + j) * 128 +
                    (((key >> 3) ^ j) << 4) + (key & 7) * 2) = (unsigned short)v[j];
            }
        }
        __syncthreads();

        // ---- QK^T: 4 col-tiles x 4 k-steps of MFMA ----
        f32x4 sacc[4];
#pragma unroll
        for (int ct = 0; ct < 4; ++ct) sacc[ct] = (f32x4){0.f, 0.f, 0.f, 0.f};
#pragma unroll
        for (int ct = 0; ct < 4; ++ct) {
            const int key = ct * 16 + l15;
            const char* krow = reinterpret_cast<const char*>(Ks) + key * 256;
            const int swz = (key & 7);
#pragma unroll
            for (int ks = 0; ks < 4; ++ks) {
                int cK = ks * 4 + l4;          // d chunk
                bf16x8 kb = *reinterpret_cast<const bf16x8*>(
                    krow + ((cK ^ swz) << 4));
                sacc[ct] = __builtin_amdgcn_mfma_f32_16x16x32_bf16(
                    qf[ks], kb, sacc[ct], 0, 0, 0);
            }
        }

        // ---- scores -> per-wave LDS (scale + causal mask on diagonal) ----
        const bool diag = (t == nt - 1);
        float* ss = Ss[w];
#pragma unroll
        for (int ct = 0; ct < 4; ++ct) {
            const int key = ct * 16 + l15;
#pragma unroll
            for (int r = 0; r < 4; ++r) {
                int qrow = l4 * 4 + r;         // local row 0..15
                float v = sacc[ct][r] * SCALE;
                if (diag && key > w * 16 + qrow) v = -1e30f;
                ss[qrow * 68 + key] = v;
            }
        }
        // (no barrier: Ss is wave-private; DS ops complete in order per wave)

        // ---- wave-parallel online softmax; P laid out as PV A-fragment ----
        // lane (row=l15) handles keys { ks2*32 + l4*8 + j : j=0..7, ks2=0..1 }
        float p[16];
        float mloc = -1e30f;
        const float* srow = ss + l15 * 68;
#pragma unroll
        for (int x = 0; x < 16; ++x) {
            int key = (x >> 3) * 32 + l4 * 8 + (x & 7);
            p[x] = srow[key];
            mloc = fmaxf(mloc, p[x]);
        }
        mloc = fmaxf(mloc, __shfl_xor(mloc, 16));
        mloc = fmaxf(mloc, __shfl_xor(mloc, 32));
        float mnew  = fmaxf(m_r, mloc);
        float alpha = __expf(m_r - mnew);
        float lsum  = 0.f;
#pragma unroll
        for (int x = 0; x < 16; ++x) {
            p[x] = __expf(p[x] - mnew);
            lsum += p[x];
        }
        lsum += __shfl_xor(lsum, 16);
        lsum += __shfl_xor(lsum, 32);
        l_r = l_r * alpha + lsum;
        m_r = mnew;

        bf16x8 pa[2];
#pragma unroll
        for (int ks2 = 0; ks2 < 2; ++ks2)
#pragma unroll
            for (int x = 0; x < 8; ++x)
                pa[ks2][x] = (short)f2bf(p[ks2 * 8 + x]);

        // ---- rescale O by alpha of its C-layout rows ----
#pragma unroll
        for (int r = 0; r < 4; ++r) {
            float ar = __shfl(alpha, l4 * 4 + r);
#pragma unroll
            for (int dt = 0; dt < 8; ++dt) oacc[dt][r] *= ar;
        }

        // ---- PV: 8 d-tiles x 2 k-steps, B = Vts (transposed V) ----
#pragma unroll
        for (int dt = 0; dt < 8; ++dt) {
            const int d   = dt * 16 + l15;
            const char* vrow = reinterpret_cast<const char*>(Vts) + d * 128;
            const int swz = (d & 7);
#pragma unroll
            for (int ks2 = 0; ks2 < 2; ++ks2) {
                int cV = ks2 * 4 + l4;         // key chunk
                bf16x8 vb = *reinterpret_cast<const bf16x8*>(
                    vrow + ((cV ^ swz) << 4));
                oacc[dt] = __builtin_amdgcn_mfma_f32_16x16x32_bf16(
                    pa[ks2], vb, oacc[dt], 0, 0, 0);
            }
        }
    }

    // ---- epilogue: normalize rows, store bf16 ----
#pragma unroll
    for (int r = 0; r < 4; ++r) {
        float lr  = __shfl(l_r, l4 * 4 + r);
        float inv = 1.0f / lr;
        unsigned short* dst =
            attn_out + (size_t)(s0 + w * 16 + l4 * 4 + r) * (NQ * HD) + h * HD;
#pragma unroll
        for (int dt = 0; dt < 8; ++dt)
            dst[dt * 16 + l15] = f2bf(oacc[dt][r] * inv);
    }
}

// ---------------------------------------------------------------------------
extern "C" void kernel_launch(void* const* d_in, const int* in_sizes, int n_in,
                              void* d_out, int out_size, void* d_ws, size_t ws_size,
                              hipStream_t stream)
{
    const int*   positions = (const int*)d_in[0];     // int32/int64 (detected)
    const float* hidden    = (const float*)d_in[1];   // S x 4096 fp32
    const float* w_qkv     = (const float*)d_in[2];   // 4096 x 6144 fp32
    const float* w_o       = (const float*)d_in[3];   // 4096 x 4096 fp32
    const int S = in_sizes[0];

    // Workspace: qkv (S x 6144 bf16) then attn (S x 4096 bf16) = 80 MB total
    unsigned short* qkv  = (unsigned short*)d_ws;
    unsigned short* attn = qkv + (size_t)S * NQKV;

    // 1) QKV projection (fp32 x fp32 -> bf16 ws)
    dim3 g1(NQKV / BN, S / BM);
    gemm_f32acc<float, float, unsigned short><<<g1, 256, 0, stream>>>(
        hidden, w_qkv, qkv, S, NQKV, H_DIM);

    // 2) RoPE on Q and K regions (in place, bf16)
    int total = S * (NQ + NKV) * (HD / 2);
    rope_kernel<<<(total + 255) / 256, 256, 0, stream>>>(qkv, positions, S);

    // 3) Causal GQA flash attention, MFMA (bf16 -> bf16 ws)
    dim3 g3(S / 64, NQ);
    attn_mfma<<<g3, 256, 0, stream>>>(qkv, attn, S);

    // 4) Output projection -> d_out (bf16 x fp32 -> fp32 out)
    dim3 g4(H_DIM / BN, S / BM);
    gemm_f32acc<unsigned short, float, float><<<g4, 256, 0, stream>>>(
        attn, w_o, (float*)d_out, S, H_DIM, H_DIM);
}

// Round 2
// 1291.219 us; speedup vs baseline: 8.1453x; 3.5712x over previous
//
#include <hip/hip_runtime.h>
#include <hip/hip_bf16.h>
#include <math.h>

// Problem constants (fixed by the reference)
#define H_DIM 4096
#define NQ    32
#define NKV   8
#define HD    128
#define GRPQ  4
#define NQKV  6144      // NQ*HD + 2*NKV*HD
#define KOFF  4096      // column offset of K region in qkv
#define VOFF  5120      // column offset of V region in qkv
#define SCALE 0.08838834764831844f   // 128^-0.5

typedef float f32x4 __attribute__((ext_vector_type(4)));
typedef short bf16x8 __attribute__((ext_vector_type(8)));

static __device__ __forceinline__ float bf2f(unsigned short u) {
    return __uint_as_float(((unsigned int)u) << 16);
}
static __device__ __forceinline__ unsigned short f2bf(float f) {
    return __bfloat16_as_ushort(__float2bfloat16(f));
}

// Async global->LDS, 16B per lane. LDS dest is wave-uniform base; HW writes
// lane i at base + i*16. Global src is per-lane.
static __device__ __forceinline__ void gload_lds16(const void* g, void* l) {
    __builtin_amdgcn_global_load_lds(
        (const __attribute__((address_space(1))) unsigned int*)g,
        (__attribute__((address_space(3))) unsigned int*)l, 16, 0, 0);
}

// 4-element vector load -> float4, overloaded on source dtype.
static __device__ __forceinline__ float4 load4(const float* p) {
    return *reinterpret_cast<const float4*>(p);
}
static __device__ __forceinline__ float4 load4(const unsigned short* p) {
    ushort4 v = *reinterpret_cast<const ushort4*>(p);
    return make_float4(bf2f(v.x), bf2f(v.y), bf2f(v.z), bf2f(v.w));
}

// Scalar store, overloaded on destination dtype (fp32 or bf16-bits).
static __device__ __forceinline__ void store1(float* p, float v) { *p = v; }
static __device__ __forceinline__ void store1(unsigned short* p, float v) {
    *p = f2bf(v);
}

// ---------------------------------------------------------------------------
// Fallback fp32 GEMM (used only if workspace is too small for the bf16 path).
// ---------------------------------------------------------------------------
#define BM 128
#define BN 128
#define BK 16
#define LPAD 4

template <typename TA, typename TB, typename TC>
__global__ __launch_bounds__(256) void gemm_f32acc(
    const TA* __restrict__ A,
    const TB* __restrict__ B,
    TC* __restrict__ C,
    int M, int N, int K)
{
    __shared__ float As[BK][BM + LPAD];
    __shared__ float Bs[BK][BN + LPAD];

    const int tid = threadIdx.x;
    const int bm  = blockIdx.y * BM;
    const int bn  = blockIdx.x * BN;
    const int tx  = tid & 15;
    const int ty  = tid >> 4;

    float acc[8][8];
#pragma unroll
    for (int i = 0; i < 8; ++i)
#pragma unroll
        for (int j = 0; j < 8; ++j) acc[i][j] = 0.0f;

    for (int k0 = 0; k0 < K; k0 += BK) {
        for (int q = tid; q < (BM * BK) / 4; q += 256) {
            int row = q >> 2;
            int kq  = (q & 3) << 2;
            float4 v = load4(&A[(size_t)(bm + row) * K + k0 + kq]);
            As[kq + 0][row] = v.x;
            As[kq + 1][row] = v.y;
            As[kq + 2][row] = v.z;
            As[kq + 3][row] = v.w;
        }
        for (int q = tid; q < (BK * BN) / 4; q += 256) {
            int k = q >> 5;
            int n = (q & 31) << 2;
            float4 v = load4(&B[(size_t)(k0 + k) * N + bn + n]);
            Bs[k][n + 0] = v.x;
            Bs[k][n + 1] = v.y;
            Bs[k][n + 2] = v.z;
            Bs[k][n + 3] = v.w;
        }
        __syncthreads();

#pragma unroll
        for (int k = 0; k < BK; ++k) {
            float a[8], b[8];
#pragma unroll
            for (int i = 0; i < 8; ++i) a[i] = As[k][ty * 8 + i];
#pragma unroll
            for (int j = 0; j < 8; ++j) b[j] = Bs[k][tx * 8 + j];
#pragma unroll
            for (int i = 0; i < 8; ++i)
#pragma unroll
                for (int j = 0; j < 8; ++j) acc[i][j] += a[i] * b[j];
        }
        __syncthreads();
    }

#pragma unroll
    for (int i = 0; i < 8; ++i) {
        size_t r = (size_t)(bm + ty * 8 + i);
#pragma unroll
        for (int j = 0; j < 8; ++j) {
            int c = bn + tx * 8 + j;
            store1(&C[r * N + c], acc[i][j]);
        }
    }
}

// ---------------------------------------------------------------------------
// fp32 -> bf16 elementwise convert (vectorized, grid-stride).
// ---------------------------------------------------------------------------
__global__ __launch_bounds__(256) void cvt_f32_bf16(
    const float4* __restrict__ src, ushort4* __restrict__ dst, int n4)
{
    int i = blockIdx.x * 256 + threadIdx.x;
    int stride = gridDim.x * 256;
    for (; i < n4; i += stride) {
        float4 v = src[i];
        dst[i] = make_ushort4(f2bf(v.x), f2bf(v.y), f2bf(v.z), f2bf(v.w));
    }
}

// ---------------------------------------------------------------------------
// fp32 [R][C] -> bf16 [C][R] transpose-convert, 32x32 LDS tiles.
// R, C multiples of 32.
// ---------------------------------------------------------------------------
__global__ __launch_bounds__(256) void transpose_f32_bf16(
    const float* __restrict__ src, unsigned short* __restrict__ dst,
    int R, int C)
{
    __shared__ unsigned short tile[32][33];
    const int r0 = blockIdx.y * 32;
    const int c0 = blockIdx.x * 32;
    const int t  = threadIdx.x;
    const int lr  = t >> 3;          // 0..31
    const int lc4 = (t & 7) << 2;    // 0,4,..,28

    float4 v = load4(&src[(size_t)(r0 + lr) * C + c0 + lc4]);
    tile[lr][lc4 + 0] = f2bf(v.x);
    tile[lr][lc4 + 1] = f2bf(v.y);
    tile[lr][lc4 + 2] = f2bf(v.z);
    tile[lr][lc4 + 3] = f2bf(v.w);
    __syncthreads();

    ushort4 o = make_ushort4(tile[lc4 + 0][lr], tile[lc4 + 1][lr],
                             tile[lc4 + 2][lr], tile[lc4 + 3][lr]);
    *reinterpret_cast<ushort4*>(&dst[(size_t)(c0 + lr) * R + r0 + lc4]) = o;
}

// ---------------------------------------------------------------------------
// MFMA bf16 GEMM (m97 structure): C[M,N] = A[M,K] @ BT[N,K]^T, fp32 accum.
// 128x128 tile, BK=32, 4 waves (2x2), 64x64 per wave, global_load_lds w=16.
// LDS tiles are LINEAR row-major [128][32] bf16 (required by global_load_lds);
// fragment ds_read_b128s tile the full 1KB per 16-lane row-group ->
// conflict-free.
// ---------------------------------------------------------------------------
template <typename TC>
__global__ __launch_bounds__(256) void gemm_bf16_bt(
    const unsigned short* __restrict__ A,    // [M][K] bf16 bits
    const unsigned short* __restrict__ BT,   // [N][K] bf16 bits
    TC* __restrict__ C,                      // [M][N]
    int M, int N, int K)
{
    __shared__ unsigned short As[128 * 32];  // 8 KB
    __shared__ unsigned short Bs[128 * 32];  // 8 KB

    const int tid  = threadIdx.x;
    const int lane = tid & 63;
    const int w    = tid >> 6;
    const int wr   = w >> 1;      // wave row (0..1)
    const int wc   = w & 1;       // wave col (0..1)
    const int l15  = lane & 15;
    const int l4   = lane >> 4;
    const size_t bm = (size_t)blockIdx.y * 128;
    const size_t bn = (size_t)blockIdx.x * 128;

    f32x4 acc[4][4];
#pragma unroll
    for (int mi = 0; mi < 4; ++mi)
#pragma unroll
        for (int ni = 0; ni < 4; ++ni) acc[mi][ni] = (f32x4){0.f, 0.f, 0.f, 0.f};

    for (int k0 = 0; k0 < K; k0 += 32) {
        __syncthreads();   // prior iteration's ds_reads done before overwrite
        // Stage A and B tiles: 512 16B chunks each; wave w issues chunks
        // [(w*2+it)*64 + lane]. Chunk c = row (c>>2), col-chunk (c&3).
#pragma unroll
        for (int it = 0; it < 2; ++it) {
            const int cb = (w * 2 + it) * 64;
            const int c  = cb + lane;
            gload_lds16(A  + (bm + (c >> 2)) * K + k0 + (c & 3) * 8,
                        (char*)As + cb * 16);
            gload_lds16(BT + (bn + (c >> 2)) * K + k0 + (c & 3) * 8,
                        (char*)Bs + cb * 16);
        }
        __syncthreads();

        bf16x8 a[4], b[4];
#pragma unroll
        for (int mi = 0; mi < 4; ++mi)
            a[mi] = *reinterpret_cast<const bf16x8*>(
                (char*)As + (wr * 64 + mi * 16 + l15) * 64 + l4 * 16);
#pragma unroll
        for (int ni = 0; ni < 4; ++ni)
            b[ni] = *reinterpret_cast<const bf16x8*>(
                (char*)Bs + (wc * 64 + ni * 16 + l15) * 64 + l4 * 16);
#pragma unroll
        for (int mi = 0; mi < 4; ++mi)
#pragma unroll
            for (int ni = 0; ni < 4; ++ni)
                acc[mi][ni] = __builtin_amdgcn_mfma_f32_16x16x32_bf16(
                    a[mi], b[ni], acc[mi][ni], 0, 0, 0);
    }

    // Epilogue: C/D layout col = lane&15, row = (lane>>4)*4 + reg
#pragma unroll
    for (int mi = 0; mi < 4; ++mi) {
#pragma unroll
        for (int r = 0; r < 4; ++r) {
            size_t row = bm + wr * 64 + mi * 16 + l4 * 4 + r;
#pragma unroll
            for (int ni = 0; ni < 4; ++ni) {
                size_t col = bn + wc * 64 + ni * 16 + l15;
                store1(&C[row * N + col], acc[mi][ni][r]);
            }
        }
    }
}

// ---------------------------------------------------------------------------
// RoPE applied in place to the Q and K regions of qkv (S x 6144, bf16).
// ---------------------------------------------------------------------------
__global__ __launch_bounds__(256) void rope_kernel(
    unsigned short* __restrict__ qkv,
    const int* __restrict__ pos32,
    int S)
{
    int idx = blockIdx.x * 256 + threadIdx.x;
    int total = S * (NQ + NKV) * (HD / 2);
    if (idx >= total) return;

    int j    = idx & 63;
    int head = (idx >> 6) % (NQ + NKV);
    int s    = idx / (64 * (NQ + NKV));

    const bool is64 = (pos32[1] == 0);      // int64 little-endian arange
    int pos = is64 ? pos32[2 * s] : pos32[s];

    unsigned short* row = qkv + (size_t)s * NQKV + head * HD;
    float x1 = bf2f(row[j]);
    float x2 = bf2f(row[j + 64]);

    float p = (float)pos;
    float inv_freq = powf(10000.0f, -((float)j) * (1.0f / 64.0f));
    float f = p * inv_freq;
    float sn, cs;
    sincosf(f, &sn, &cs);

    row[j]      = f2bf(x1 * cs - x2 * sn);
    row[j + 64] = f2bf(x2 * cs + x1 * sn);
}

// ---------------------------------------------------------------------------
// MFMA flash attention (bf16 in, fp32 accum, bf16 out). Verified round 1.
// ---------------------------------------------------------------------------
__global__ __launch_bounds__(256) void attn_mfma(
    const unsigned short* __restrict__ qkv,   // S x 6144 bf16 bits (RoPE'd)
    unsigned short* __restrict__ attn_out,    // S x 4096 bf16 bits
    int S)
{
    __shared__ unsigned short Ks[64 * 128];    // 16 KB
    __shared__ unsigned short Vts[128 * 64];   // 16 KB
    __shared__ float Ss[4][16 * 68];           // 17 KB (per-wave)

    const int tid  = threadIdx.x;
    const int lane = tid & 63;
    const int w    = tid >> 6;        // wave 0..3
    const int l15  = lane & 15;
    const int l4   = lane >> 4;       // quarter 0..3
    const int h    = blockIdx.y;      // query head
    const int g    = h >> 2;          // kv head
    const int s0   = blockIdx.x * 64;

    bf16x8 qf[4];
    {
        const unsigned short* qrow =
            qkv + (size_t)(s0 + w * 16 + l15) * NQKV + h * HD;
#pragma unroll
        for (int ks = 0; ks < 4; ++ks)
            qf[ks] = *reinterpret_cast<const bf16x8*>(qrow + ks * 32 + l4 * 8);
    }

    f32x4 oacc[8];
#pragma unroll
    for (int dt = 0; dt < 8; ++dt) oacc[dt] = (f32x4){0.f, 0.f, 0.f, 0.f};
    float m_r = -1e30f;
    float l_r = 0.0f;

    const int nt = blockIdx.x + 1;
    for (int t = 0; t < nt; ++t) {
        const int t0 = t * 64;
        __syncthreads();

#pragma unroll
        for (int it = 0; it < 4; ++it) {
            int cc  = tid + it * 256;
            int key = cc >> 4;
            int c   = cc & 15;
            bf16x8 v = *reinterpret_cast<const bf16x8*>(
                qkv + (size_t)(t0 + key) * NQKV + KOFF + g * HD + c * 8);
            *reinterpret_cast<bf16x8*>(
                reinterpret_cast<char*>(Ks) + key * 256 + ((c ^ (key & 7)) << 4)) = v;
        }
#pragma unroll
        for (int it = 0; it < 4; ++it) {
            int cc  = tid + it * 256;
            int key = cc & 63;
            int d0  = (cc >> 6) * 8;
            bf16x8 v = *reinterpret_cast<const bf16x8*>(
                qkv + (size_t)(t0 + key) * NQKV + VOFF + g * HD + d0);
#pragma unroll
            for (int j = 0; j < 8; ++j) {
                *reinterpret_cast<unsigned short*>(
                    reinterpret_cast<char*>(Vts) + (d0 + j) * 128 +
                    (((key >> 3) ^ j) << 4) + (key & 7) * 2) = (unsigned short)v[j];
            }
        }
        __syncthreads();

        f32x4 sacc[4];
#pragma unroll
        for (int ct = 0; ct < 4; ++ct) sacc[ct] = (f32x4){0.f, 0.f, 0.f, 0.f};
#pragma unroll
        for (int ct = 0; ct < 4; ++ct) {
            const int key = ct * 16 + l15;
            const char* krow = reinterpret_cast<const char*>(Ks) + key * 256;
            const int swz = (key & 7);
#pragma unroll
            for (int ks = 0; ks < 4; ++ks) {
                int cK = ks * 4 + l4;
                bf16x8 kb = *reinterpret_cast<const bf16x8*>(
                    krow + ((cK ^ swz) << 4));
                sacc[ct] = __builtin_amdgcn_mfma_f32_16x16x32_bf16(
                    qf[ks], kb, sacc[ct], 0, 0, 0);
            }
        }

        const bool diag = (t == nt - 1);
        float* ss = Ss[w];
#pragma unroll
        for (int ct = 0; ct < 4; ++ct) {
            const int key = ct * 16 + l15;
#pragma unroll
            for (int r = 0; r < 4; ++r) {
                int qrow = l4 * 4 + r;
                float v = sacc[ct][r] * SCALE;
                if (diag && key > w * 16 + qrow) v = -1e30f;
                ss[qrow * 68 + key] = v;
            }
        }

        float p[16];
        float mloc = -1e30f;
        const float* srow = ss + l15 * 68;
#pragma unroll
        for (int x = 0; x < 16; ++x) {
            int key = (x >> 3) * 32 + l4 * 8 + (x & 7);
            p[x] = srow[key];
            mloc = fmaxf(mloc, p[x]);
        }
        mloc = fmaxf(mloc, __shfl_xor(mloc, 16));
        mloc = fmaxf(mloc, __shfl_xor(mloc, 32));
        float mnew  = fmaxf(m_r, mloc);
        float alpha = __expf(m_r - mnew);
        float lsum  = 0.f;
#pragma unroll
        for (int x = 0; x < 16; ++x) {
            p[x] = __expf(p[x] - mnew);
            lsum += p[x];
        }
        lsum += __shfl_xor(lsum, 16);
        lsum += __shfl_xor(lsum, 32);
        l_r = l_r * alpha + lsum;
        m_r = mnew;

        bf16x8 pa[2];
#pragma unroll
        for (int ks2 = 0; ks2 < 2; ++ks2)
#pragma unroll
            for (int x = 0; x < 8; ++x)
                pa[ks2][x] = (short)f2bf(p[ks2 * 8 + x]);

#pragma unroll
        for (int r = 0; r < 4; ++r) {
            float ar = __shfl(alpha, l4 * 4 + r);
#pragma unroll
            for (int dt = 0; dt < 8; ++dt) oacc[dt][r] *= ar;
        }

#pragma unroll
        for (int dt = 0; dt < 8; ++dt) {
            const int d   = dt * 16 + l15;
            const char* vrow = reinterpret_cast<const char*>(Vts) + d * 128;
            const int swz = (d & 7);
#pragma unroll
            for (int ks2 = 0; ks2 < 2; ++ks2) {
                int cV = ks2 * 4 + l4;
                bf16x8 vb = *reinterpret_cast<const bf16x8*>(
                    vrow + ((cV ^ swz) << 4));
                oacc[dt] = __builtin_amdgcn_mfma_f32_16x16x32_bf16(
                    pa[ks2], vb, oacc[dt], 0, 0, 0);
            }
        }
    }

#pragma unroll
    for (int r = 0; r < 4; ++r) {
        float lr  = __shfl(l_r, l4 * 4 + r);
        float inv = 1.0f / lr;
        unsigned short* dst =
            attn_out + (size_t)(s0 + w * 16 + l4 * 4 + r) * (NQ * HD) + h * HD;
#pragma unroll
        for (int dt = 0; dt < 8; ++dt)
            dst[dt * 16 + l15] = f2bf(oacc[dt][r] * inv);
    }
}

// ---------------------------------------------------------------------------
extern "C" void kernel_launch(void* const* d_in, const int* in_sizes, int n_in,
                              void* d_out, int out_size, void* d_ws, size_t ws_size,
                              hipStream_t stream)
{
    const int*   positions = (const int*)d_in[0];     // int32/int64 (detected)
    const float* hidden    = (const float*)d_in[1];   // S x 4096 fp32
    const float* w_qkv     = (const float*)d_in[2];   // 4096 x 6144 fp32
    const float* w_o       = (const float*)d_in[3];   // 4096 x 4096 fp32
    const int S = in_sizes[0];
    const size_t Sz = (size_t)S;

    // Workspace layout (bf16 halves):
    //   qkv   : S x 6144
    //   attn  : S x 4096
    //   hbf   : S x 4096            (hidden in bf16)
    //   wqkvT : 6144 x 4096         (w_qkv transposed, bf16)
    //   woT   : 4096 x 4096         (w_o transposed, bf16)
    unsigned short* qkv   = (unsigned short*)d_ws;
    unsigned short* attn  = qkv   + Sz * NQKV;
    unsigned short* hbf   = attn  + Sz * H_DIM;
    unsigned short* wqkvT = hbf   + Sz * H_DIM;
    unsigned short* woT   = wqkvT + (size_t)NQKV * H_DIM;
    const size_t need = (Sz * NQKV + Sz * H_DIM + Sz * H_DIM +
                         (size_t)NQKV * H_DIM + (size_t)H_DIM * H_DIM) *
                        sizeof(unsigned short);

    if (ws_size >= need) {
        // --- bf16 MFMA path ---
        // 0a) hidden -> bf16
        int n4 = (S * H_DIM) / 4;
        int cg = (n4 + 255) / 256; if (cg > 2048) cg = 2048;
        cvt_f32_bf16<<<cg, 256, 0, stream>>>(
            (const float4*)hidden, (ushort4*)hbf, n4);
        // 0b) w_qkv [4096][6144] -> wqkvT [6144][4096] bf16
        transpose_f32_bf16<<<dim3(NQKV / 32, H_DIM / 32), 256, 0, stream>>>(
            w_qkv, wqkvT, H_DIM, NQKV);
        // 0c) w_o [4096][4096] -> woT bf16
        transpose_f32_bf16<<<dim3(H_DIM / 32, H_DIM / 32), 256, 0, stream>>>(
            w_o, woT, H_DIM, H_DIM);

        // 1) QKV projection: qkv = hbf @ wqkvT^T  (bf16 MFMA, fp32 accum)
        gemm_bf16_bt<unsigned short><<<dim3(NQKV / 128, S / 128), 256, 0, stream>>>(
            hbf, wqkvT, qkv, S, NQKV, H_DIM);

        // 2) RoPE on Q and K regions (in place, bf16)
        int total = S * (NQ + NKV) * (HD / 2);
        rope_kernel<<<(total + 255) / 256, 256, 0, stream>>>(qkv, positions, S);

        // 3) Causal GQA flash attention, MFMA (bf16 -> bf16 ws)
        attn_mfma<<<dim3(S / 64, NQ), 256, 0, stream>>>(qkv, attn, S);

        // 4) Output projection -> d_out (fp32)
        gemm_bf16_bt<float><<<dim3(H_DIM / 128, S / 128), 256, 0, stream>>>(
            attn, woT, (float*)d_out, S, H_DIM, H_DIM);
    } else {
        // --- fallback: round-1 fp32-GEMM path (80 MB workspace) ---
        gemm_f32acc<float, float, unsigned short>
            <<<dim3(NQKV / BN, S / BM), 256, 0, stream>>>(
                hidden, w_qkv, qkv, S, NQKV, H_DIM);
        int total = S * (NQ + NKV) * (HD / 2);
        rope_kernel<<<(total + 255) / 256, 256, 0, stream>>>(qkv, positions, S);
        attn_mfma<<<dim3(S / 64, NQ), 256, 0, stream>>>(qkv, attn, S);
        gemm_f32acc<unsigned short, float, float>
            <<<dim3(H_DIM / BN, S / BM), 256, 0, stream>>>(
                attn, w_o, (float*)d_out, S, H_DIM, H_DIM);
    }
}

// Round 3
// 1070.528 us; speedup vs baseline: 9.8245x; 1.2062x over previous
//
#include <hip/hip_runtime.h>
#include <hip/hip_bf16.h>
#include <math.h>

// Problem constants (fixed by the reference)
#define H_DIM 4096
#define NQ    32
#define NKV   8
#define HD    128
#define GRPQ  4
#define NQKV  6144      // NQ*HD + 2*NKV*HD
#define KOFF  4096      // column offset of K region in qkv
#define VOFF  5120      // column offset of V region in qkv
#define SCALE 0.08838834764831844f   // 128^-0.5

typedef float f32x4 __attribute__((ext_vector_type(4)));
typedef short bf16x8 __attribute__((ext_vector_type(8)));

static __device__ __forceinline__ float bf2f(unsigned short u) {
    return __uint_as_float(((unsigned int)u) << 16);
}
static __device__ __forceinline__ unsigned short f2bf(float f) {
    return __bfloat16_as_ushort(__float2bfloat16(f));
}

// Async global->LDS, 16B per lane. LDS dest is wave-uniform base; HW writes
// lane i at base + i*16. Global src is per-lane.
static __device__ __forceinline__ void gload_lds16(const void* g, void* l) {
    __builtin_amdgcn_global_load_lds(
        (const __attribute__((address_space(1))) unsigned int*)g,
        (__attribute__((address_space(3))) unsigned int*)l, 16, 0, 0);
}

// 4-element vector load -> float4, overloaded on source dtype.
static __device__ __forceinline__ float4 load4(const float* p) {
    return *reinterpret_cast<const float4*>(p);
}
static __device__ __forceinline__ float4 load4(const unsigned short* p) {
    ushort4 v = *reinterpret_cast<const ushort4*>(p);
    return make_float4(bf2f(v.x), bf2f(v.y), bf2f(v.z), bf2f(v.w));
}

// Scalar store, overloaded on destination dtype (fp32 or bf16-bits).
static __device__ __forceinline__ void store1(float* p, float v) { *p = v; }
static __device__ __forceinline__ void store1(unsigned short* p, float v) {
    *p = f2bf(v);
}

// ---------------------------------------------------------------------------
// Fallback fp32 GEMM (used only if workspace is too small for the bf16 path).
// ---------------------------------------------------------------------------
#define BM 128
#define BN 128
#define BK 16
#define LPAD 4

template <typename TA, typename TB, typename TC>
__global__ __launch_bounds__(256) void gemm_f32acc(
    const TA* __restrict__ A,
    const TB* __restrict__ B,
    TC* __restrict__ C,
    int M, int N, int K)
{
    __shared__ float As[BK][BM + LPAD];
    __shared__ float Bs[BK][BN + LPAD];

    const int tid = threadIdx.x;
    const int bm  = blockIdx.y * BM;
    const int bn  = blockIdx.x * BN;
    const int tx  = tid & 15;
    const int ty  = tid >> 4;

    float acc[8][8];
#pragma unroll
    for (int i = 0; i < 8; ++i)
#pragma unroll
        for (int j = 0; j < 8; ++j) acc[i][j] = 0.0f;

    for (int k0 = 0; k0 < K; k0 += BK) {
        for (int q = tid; q < (BM * BK) / 4; q += 256) {
            int row = q >> 2;
            int kq  = (q & 3) << 2;
            float4 v = load4(&A[(size_t)(bm + row) * K + k0 + kq]);
            As[kq + 0][row] = v.x;
            As[kq + 1][row] = v.y;
            As[kq + 2][row] = v.z;
            As[kq + 3][row] = v.w;
        }
        for (int q = tid; q < (BK * BN) / 4; q += 256) {
            int k = q >> 5;
            int n = (q & 31) << 2;
            float4 v = load4(&B[(size_t)(k0 + k) * N + bn + n]);
            Bs[k][n + 0] = v.x;
            Bs[k][n + 1] = v.y;
            Bs[k][n + 2] = v.z;
            Bs[k][n + 3] = v.w;
        }
        __syncthreads();

#pragma unroll
        for (int k = 0; k < BK; ++k) {
            float a[8], b[8];
#pragma unroll
            for (int i = 0; i < 8; ++i) a[i] = As[k][ty * 8 + i];
#pragma unroll
            for (int j = 0; j < 8; ++j) b[j] = Bs[k][tx * 8 + j];
#pragma unroll
            for (int i = 0; i < 8; ++i)
#pragma unroll
                for (int j = 0; j < 8; ++j) acc[i][j] += a[i] * b[j];
        }
        __syncthreads();
    }

#pragma unroll
    for (int i = 0; i < 8; ++i) {
        size_t r = (size_t)(bm + ty * 8 + i);
#pragma unroll
        for (int j = 0; j < 8; ++j) {
            int c = bn + tx * 8 + j;
            store1(&C[r * N + c], acc[i][j]);
        }
    }
}

// ---------------------------------------------------------------------------
// fp32 -> bf16 elementwise convert (vectorized, grid-stride).
// ---------------------------------------------------------------------------
__global__ __launch_bounds__(256) void cvt_f32_bf16(
    const float4* __restrict__ src, ushort4* __restrict__ dst, int n4)
{
    int i = blockIdx.x * 256 + threadIdx.x;
    int stride = gridDim.x * 256;
    for (; i < n4; i += stride) {
        float4 v = src[i];
        dst[i] = make_ushort4(f2bf(v.x), f2bf(v.y), f2bf(v.z), f2bf(v.w));
    }
}

// ---------------------------------------------------------------------------
// fp32 [R][C] -> bf16 [C][R] transpose-convert, 32x32 LDS tiles.
// ---------------------------------------------------------------------------
__global__ __launch_bounds__(256) void transpose_f32_bf16(
    const float* __restrict__ src, unsigned short* __restrict__ dst,
    int R, int C)
{
    __shared__ unsigned short tile[32][33];
    const int r0 = blockIdx.y * 32;
    const int c0 = blockIdx.x * 32;
    const int t  = threadIdx.x;
    const int lr  = t >> 3;          // 0..31
    const int lc4 = (t & 7) << 2;    // 0,4,..,28

    float4 v = load4(&src[(size_t)(r0 + lr) * C + c0 + lc4]);
    tile[lr][lc4 + 0] = f2bf(v.x);
    tile[lr][lc4 + 1] = f2bf(v.y);
    tile[lr][lc4 + 2] = f2bf(v.z);
    tile[lr][lc4 + 3] = f2bf(v.w);
    __syncthreads();

    ushort4 o = make_ushort4(tile[lc4 + 0][lr], tile[lc4 + 1][lr],
                             tile[lc4 + 2][lr], tile[lc4 + 3][lr]);
    *reinterpret_cast<ushort4*>(&dst[(size_t)(c0 + lr) * R + r0 + lc4]) = o;
}

// ---------------------------------------------------------------------------
// MFMA bf16 GEMM (m97 structure): C[M,N] = A[M,K] @ BT[N,K]^T, fp32 accum.
// ---------------------------------------------------------------------------
template <typename TC>
__global__ __launch_bounds__(256) void gemm_bf16_bt(
    const unsigned short* __restrict__ A,    // [M][K] bf16 bits
    const unsigned short* __restrict__ BT,   // [N][K] bf16 bits
    TC* __restrict__ C,                      // [M][N]
    int M, int N, int K)
{
    __shared__ unsigned short As[128 * 32];  // 8 KB
    __shared__ unsigned short Bs[128 * 32];  // 8 KB

    const int tid  = threadIdx.x;
    const int lane = tid & 63;
    const int w    = tid >> 6;
    const int wr   = w >> 1;
    const int wc   = w & 1;
    const int l15  = lane & 15;
    const int l4   = lane >> 4;
    const size_t bm = (size_t)blockIdx.y * 128;
    const size_t bn = (size_t)blockIdx.x * 128;

    f32x4 acc[4][4];
#pragma unroll
    for (int mi = 0; mi < 4; ++mi)
#pragma unroll
        for (int ni = 0; ni < 4; ++ni) acc[mi][ni] = (f32x4){0.f, 0.f, 0.f, 0.f};

    for (int k0 = 0; k0 < K; k0 += 32) {
        __syncthreads();
#pragma unroll
        for (int it = 0; it < 2; ++it) {
            const int cb = (w * 2 + it) * 64;
            const int c  = cb + lane;
            gload_lds16(A  + (bm + (c >> 2)) * K + k0 + (c & 3) * 8,
                        (char*)As + cb * 16);
            gload_lds16(BT + (bn + (c >> 2)) * K + k0 + (c & 3) * 8,
                        (char*)Bs + cb * 16);
        }
        __syncthreads();

        bf16x8 a[4], b[4];
#pragma unroll
        for (int mi = 0; mi < 4; ++mi)
            a[mi] = *reinterpret_cast<const bf16x8*>(
                (char*)As + (wr * 64 + mi * 16 + l15) * 64 + l4 * 16);
#pragma unroll
        for (int ni = 0; ni < 4; ++ni)
            b[ni] = *reinterpret_cast<const bf16x8*>(
                (char*)Bs + (wc * 64 + ni * 16 + l15) * 64 + l4 * 16);
#pragma unroll
        for (int mi = 0; mi < 4; ++mi)
#pragma unroll
            for (int ni = 0; ni < 4; ++ni)
                acc[mi][ni] = __builtin_amdgcn_mfma_f32_16x16x32_bf16(
                    a[mi], b[ni], acc[mi][ni], 0, 0, 0);
    }

#pragma unroll
    for (int mi = 0; mi < 4; ++mi) {
#pragma unroll
        for (int r = 0; r < 4; ++r) {
            size_t row = bm + wr * 64 + mi * 16 + l4 * 4 + r;
#pragma unroll
            for (int ni = 0; ni < 4; ++ni) {
                size_t col = bn + wc * 64 + ni * 16 + l15;
                store1(&C[row * N + col], acc[mi][ni][r]);
            }
        }
    }
}

// ---------------------------------------------------------------------------
// RoPE applied in place to the Q and K regions of qkv (S x 6144, bf16).
// ---------------------------------------------------------------------------
__global__ __launch_bounds__(256) void rope_kernel(
    unsigned short* __restrict__ qkv,
    const int* __restrict__ pos32,
    int S)
{
    int idx = blockIdx.x * 256 + threadIdx.x;
    int total = S * (NQ + NKV) * (HD / 2);
    if (idx >= total) return;

    int j    = idx & 63;
    int head = (idx >> 6) % (NQ + NKV);
    int s    = idx / (64 * (NQ + NKV));

    const bool is64 = (pos32[1] == 0);      // int64 little-endian arange
    int pos = is64 ? pos32[2 * s] : pos32[s];

    unsigned short* row = qkv + (size_t)s * NQKV + head * HD;
    float x1 = bf2f(row[j]);
    float x2 = bf2f(row[j + 64]);

    float p = (float)pos;
    float inv_freq = powf(10000.0f, -((float)j) * (1.0f / 64.0f));
    float f = p * inv_freq;
    float sn, cs;
    sincosf(f, &sn, &cs);

    row[j]      = f2bf(x1 * cs - x2 * sn);
    row[j + 64] = f2bf(x2 * cs + x1 * sn);
}

// ---------------------------------------------------------------------------
// MFMA flash attention v3: swapped QK^T + in-register softmax + slot-permuted
// V. Block = 4 waves; wave w owns 32 q-rows [s0+32w, s0+32w+32). KVBLK = 64.
//
//  QK^T : mfma(A=K, B=Q) -> D[m=key][n=qrow]; lane col = qrow, so each lane's
//         sacc holds P-row fragments for its TWO q-rows (qt=0,1) -> softmax is
//         in-register (max/sum via 2x shfl_xor). No score LDS round-trip.
//  P->PV: P regs pack DIRECTLY into PV A-fragments because V is staged with
//         key rows permuted by slot(kappa) = 32*(kt>>1) + 8*q + 4*(kt&1) + r
//         (kt=kappa>>4, q=(kappa>>2)&3, r=kappa&3). Contraction over keys is
//         permutation-invariant. Zero cross-lane exchange.
//  K    : staged via global_load_lds (linear LDS dest, pre-swizzled global
//         source: chunk c holds d-chunk c^(key&7)).
//  V^T  : reg-staged u16 scatter (64 lanes fill one 128B row per step: 2-way,
//         free). Rows XOR-swizzled chunk^(d&7) -> conflict-free b128 reads.
//  T13  : defer-max (THR=8) skips O-rescale when running max doesn't grow.
// ---------------------------------------------------------------------------
__global__ __launch_bounds__(256, 2) void attn_mfma(
    const unsigned short* __restrict__ qkv,   // S x 6144 bf16 bits (RoPE'd)
    unsigned short* __restrict__ attn_out,    // S x 4096 bf16 bits
    int S)
{
    __shared__ unsigned short Ks[64 * 128];    // 16 KB (rows 256B, swizzled)
    __shared__ unsigned short Vts[128 * 64];   // 16 KB (V^T, slot-permuted)

    const int tid  = threadIdx.x;
    const int lane = tid & 63;
    const int w    = tid >> 6;        // wave 0..3
    const int l15  = lane & 15;
    const int l4   = lane >> 4;       // quarter 0..3
    const int h    = blockIdx.y;      // query head
    const int g    = h >> 2;          // kv head
    const int xb   = (int)gridDim.x - 1 - (int)blockIdx.x;  // heavy-first
    const int s0   = xb * 128;
    const int qw   = s0 + w * 32;     // wave q range

    // Q B-fragments, pre-scaled: qf[qt][ks] -> Q[qw+qt*16+l15][ks*32+l4*8 ..]
    bf16x8 qf[2][4];
#pragma unroll
    for (int qt = 0; qt < 2; ++qt) {
        const unsigned short* qrow =
            qkv + (size_t)(qw + qt * 16 + l15) * NQKV + h * HD;
#pragma unroll
        for (int ks = 0; ks < 4; ++ks) {
            bf16x8 v = *reinterpret_cast<const bf16x8*>(qrow + ks * 32 + l4 * 8);
            bf16x8 o;
#pragma unroll
            for (int i = 0; i < 8; ++i)
                o[i] = (short)f2bf(bf2f((unsigned short)v[i]) * SCALE);
            qf[qt][ks] = o;
        }
    }

    f32x4 oacc[2][8];
#pragma unroll
    for (int qt = 0; qt < 2; ++qt)
#pragma unroll
        for (int dt = 0; dt < 8; ++dt) oacc[qt][dt] = (f32x4){0.f, 0.f, 0.f, 0.f};
    float m_r[2] = {-1e30f, -1e30f};   // running max for qrow qt*16+l15
    float l_r[2] = {0.f, 0.f};

    const int nt_max = 2 * xb + 2;
    const int nt_w   = 2 * xb + 1 + (w >> 1);   // waves 0,1 need one tile less

    for (int t = 0; t < nt_max; ++t) {
        const int t0 = t * 64;
        __syncthreads();   // prior tile's LDS reads done

        // ---- stage K via global_load_lds (pre-swizzled source) ----
#pragma unroll
        for (int it = 0; it < 4; ++it) {
            const int seg  = it * 4 + w;          // 16 segments of 64 chunks
            const int clin = seg * 64 + lane;
            const int key  = clin >> 4;
            const int csrc = (clin & 15) ^ (key & 7);
            gload_lds16(qkv + (size_t)(t0 + key) * NQKV + KOFF + g * HD + csrc * 8,
                        (char*)Ks + (size_t)seg * 1024);
        }
        // ---- stage V^T, slot-permuted keys, swizzled rows ----
#pragma unroll
        for (int it = 0; it < 4; ++it) {
            const int cc  = tid + it * 256;
            const int key = cc & 63;              // = lane (scatter-friendly)
            const int d0  = (cc >> 6) * 8;
            bf16x8 v = *reinterpret_cast<const bf16x8*>(
                qkv + (size_t)(t0 + key) * NQKV + VOFF + g * HD + d0);
            const int kt   = key >> 4;
            const int slot = 32 * (kt >> 1) + 8 * ((key >> 2) & 3) +
                             4 * (kt & 1) + (key & 3);
#pragma unroll
            for (int j = 0; j < 8; ++j) {
                const int d = d0 + j;
                *reinterpret_cast<unsigned short*>(
                    (char*)Vts + d * 128 + ((((slot >> 3) ^ (d & 7))) << 4) +
                    (slot & 7) * 2) = (unsigned short)v[j];
            }
        }
        __syncthreads();

        if (t >= nt_w) continue;   // wave's q-rows don't see these keys

        // ---- QK^T: D[key][qrow], A=K-frag from LDS, B=Q regs ----
        f32x4 sacc[4][2];
#pragma unroll
        for (int kt = 0; kt < 4; ++kt) {
            sacc[kt][0] = (f32x4){0.f, 0.f, 0.f, 0.f};
            sacc[kt][1] = (f32x4){0.f, 0.f, 0.f, 0.f};
        }
#pragma unroll
        for (int kt = 0; kt < 4; ++kt) {
            const int key = kt * 16 + l15;
            const char* krow = (const char*)Ks + key * 256;
            const int swz = key & 7;
#pragma unroll
            for (int ks = 0; ks < 4; ++ks) {
                bf16x8 kb = *reinterpret_cast<const bf16x8*>(
                    krow + (((ks * 4 + l4) ^ swz) << 4));
                sacc[kt][0] = __builtin_amdgcn_mfma_f32_16x16x32_bf16(
                    kb, qf[0][ks], sacc[kt][0], 0, 0, 0);
                sacc[kt][1] = __builtin_amdgcn_mfma_f32_16x16x32_bf16(
                    kb, qf[1][ks], sacc[kt][1], 0, 0, 0);
            }
        }

        // ---- causal mask (wave's diagonal tile only) ----
        if (t == nt_w - 1) {
#pragma unroll
            for (int kt = 0; kt < 4; ++kt) {
                const int keyb = t0 + kt * 16 + l4 * 4;
#pragma unroll
                for (int qt = 0; qt < 2; ++qt) {
                    const int qrow = qw + qt * 16 + l15;
#pragma unroll
                    for (int r = 0; r < 4; ++r)
                        if (keyb + r > qrow) sacc[kt][qt][r] = -1e30f;
                }
            }
        }

        // ---- in-register online softmax (defer-max, THR=8) ----
        float pmax[2];
#pragma unroll
        for (int qt = 0; qt < 2; ++qt) {
            float mx = sacc[0][qt][0];
#pragma unroll
            for (int kt = 0; kt < 4; ++kt)
#pragma unroll
                for (int r = 0; r < 4; ++r) mx = fmaxf(mx, sacc[kt][qt][r]);
            mx = fmaxf(mx, __shfl_xor(mx, 16));
            mx = fmaxf(mx, __shfl_xor(mx, 32));
            pmax[qt] = mx;
        }
        const bool need = (pmax[0] > m_r[0] + 8.f) || (pmax[1] > m_r[1] + 8.f);
        if (__any(need)) {   // rare rescale path
#pragma unroll
            for (int qt = 0; qt < 2; ++qt) {
                float mnew  = fmaxf(m_r[qt], pmax[qt]);
                float alpha = __expf(m_r[qt] - mnew);
                l_r[qt] *= alpha;
                m_r[qt]  = mnew;
#pragma unroll
                for (int r = 0; r < 4; ++r) {
                    float ar = __shfl(alpha, l4 * 4 + r);
#pragma unroll
                    for (int dt = 0; dt < 8; ++dt) oacc[qt][dt][r] *= ar;
                }
            }
        }

        // ---- P = exp(s - m), pack into PV A-fragments (slot order) ----
        bf16x8 pa[2][2];   // [qt][ks2]; elem j = 4*(kt&1)+r, ks2 = kt>>1
#pragma unroll
        for (int qt = 0; qt < 2; ++qt) {
            float lsum = 0.f;
#pragma unroll
            for (int kt = 0; kt < 4; ++kt) {
#pragma unroll
                for (int r = 0; r < 4; ++r) {
                    float p = __expf(sacc[kt][qt][r] - m_r[qt]);
                    lsum += p;
                    pa[qt][kt >> 1][4 * (kt & 1) + r] = (short)f2bf(p);
                }
            }
            lsum += __shfl_xor(lsum, 16);
            lsum += __shfl_xor(lsum, 32);
            l_r[qt] += lsum;
        }

        // ---- PV: O[qrow][d] += P @ Vperm ----
#pragma unroll
        for (int dt = 0; dt < 8; ++dt) {
            const int d = dt * 16 + l15;
            const char* vrow = (const char*)Vts + d * 128;
            const int swz = d & 7;
#pragma unroll
            for (int ks2 = 0; ks2 < 2; ++ks2) {
                bf16x8 vb = *reinterpret_cast<const bf16x8*>(
                    vrow + (((ks2 * 4 + l4) ^ swz) << 4));
                oacc[0][dt] = __builtin_amdgcn_mfma_f32_16x16x32_bf16(
                    pa[0][ks2], vb, oacc[0][dt], 0, 0, 0);
                oacc[1][dt] = __builtin_amdgcn_mfma_f32_16x16x32_bf16(
                    pa[1][ks2], vb, oacc[1][dt], 0, 0, 0);
            }
        }
    }

    // ---- epilogue: normalize rows (O row = qt*16 + l4*4 + r), store bf16 ----
#pragma unroll
    for (int qt = 0; qt < 2; ++qt) {
        float linv_own = 1.0f / l_r[qt];
#pragma unroll
        for (int r = 0; r < 4; ++r) {
            float linv = __shfl(linv_own, l4 * 4 + r);
            const int row = qw + qt * 16 + l4 * 4 + r;
            unsigned short* dst = attn_out + (size_t)row * (NQ * HD) + h * HD;
#pragma unroll
            for (int dt = 0; dt < 8; ++dt)
                dst[dt * 16 + l15] = f2bf(oacc[qt][dt][r] * linv);
        }
    }
}

// ---------------------------------------------------------------------------
extern "C" void kernel_launch(void* const* d_in, const int* in_sizes, int n_in,
                              void* d_out, int out_size, void* d_ws, size_t ws_size,
                              hipStream_t stream)
{
    const int*   positions = (const int*)d_in[0];     // int32/int64 (detected)
    const float* hidden    = (const float*)d_in[1];   // S x 4096 fp32
    const float* w_qkv     = (const float*)d_in[2];   // 4096 x 6144 fp32
    const float* w_o       = (const float*)d_in[3];   // 4096 x 4096 fp32
    const int S = in_sizes[0];
    const size_t Sz = (size_t)S;

    // Workspace layout (bf16 halves)
    unsigned short* qkv   = (unsigned short*)d_ws;
    unsigned short* attn  = qkv   + Sz * NQKV;
    unsigned short* hbf   = attn  + Sz * H_DIM;
    unsigned short* wqkvT = hbf   + Sz * H_DIM;
    unsigned short* woT   = wqkvT + (size_t)NQKV * H_DIM;
    const size_t need = (Sz * NQKV + Sz * H_DIM + Sz * H_DIM +
                         (size_t)NQKV * H_DIM + (size_t)H_DIM * H_DIM) *
                        sizeof(unsigned short);

    if (ws_size >= need) {
        // 0a) hidden -> bf16
        int n4 = (S * H_DIM) / 4;
        int cg = (n4 + 255) / 256; if (cg > 2048) cg = 2048;
        cvt_f32_bf16<<<cg, 256, 0, stream>>>(
            (const float4*)hidden, (ushort4*)hbf, n4);
        // 0b) w_qkv [4096][6144] -> wqkvT [6144][4096] bf16
        transpose_f32_bf16<<<dim3(NQKV / 32, H_DIM / 32), 256, 0, stream>>>(
            w_qkv, wqkvT, H_DIM, NQKV);
        // 0c) w_o [4096][4096] -> woT bf16
        transpose_f32_bf16<<<dim3(H_DIM / 32, H_DIM / 32), 256, 0, stream>>>(
            w_o, woT, H_DIM, H_DIM);

        // 1) QKV projection (bf16 MFMA, fp32 accum)
        gemm_bf16_bt<unsigned short><<<dim3(NQKV / 128, S / 128), 256, 0, stream>>>(
            hbf, wqkvT, qkv, S, NQKV, H_DIM);

        // 2) RoPE on Q and K regions (in place, bf16)
        int total = S * (NQ + NKV) * (HD / 2);
        rope_kernel<<<(total + 255) / 256, 256, 0, stream>>>(qkv, positions, S);

        // 3) Causal GQA flash attention v3 (bf16 -> bf16 ws)
        attn_mfma<<<dim3(S / 128, NQ), 256, 0, stream>>>(qkv, attn, S);

        // 4) Output projection -> d_out (fp32)
        gemm_bf16_bt<float><<<dim3(H_DIM / 128, S / 128), 256, 0, stream>>>(
            attn, woT, (float*)d_out, S, H_DIM, H_DIM);
    } else {
        // --- fallback: fp32-GEMM path (80 MB workspace) ---
        gemm_f32acc<float, float, unsigned short>
            <<<dim3(NQKV / BN, S / BM), 256, 0, stream>>>(
                hidden, w_qkv, qkv, S, NQKV, H_DIM);
        int total = S * (NQ + NKV) * (HD / 2);
        rope_kernel<<<(total + 255) / 256, 256, 0, stream>>>(qkv, positions, S);
        attn_mfma<<<dim3(S / 128, NQ), 256, 0, stream>>>(qkv, attn, S);
        gemm_f32acc<unsigned short, float, float>
            <<<dim3(H_DIM / BN, S / BM), 256, 0, stream>>>(
                attn, w_o, (float*)d_out, S, H_DIM, H_DIM);
    }
}

// Round 4
// 1059.965 us; speedup vs baseline: 9.9224x; 1.0100x over previous
//
#include <hip/hip_runtime.h>
#include <hip/hip_bf16.h>
#include <math.h>

// Problem constants (fixed by the reference)
#define H_DIM 4096
#define NQ    32
#define NKV   8
#define HD    128
#define GRPQ  4
#define NQKV  6144      // NQ*HD + 2*NKV*HD
#define KOFF  4096      // column offset of K region in qkv
#define VOFF  5120      // column offset of V region in qkv
#define SCALE 0.08838834764831844f   // 128^-0.5

typedef float f32x4 __attribute__((ext_vector_type(4)));
typedef short bf16x8 __attribute__((ext_vector_type(8)));

static __device__ __forceinline__ float bf2f(unsigned short u) {
    return __uint_as_float(((unsigned int)u) << 16);
}
static __device__ __forceinline__ unsigned short f2bf(float f) {
    return __bfloat16_as_ushort(__float2bfloat16(f));
}

// Async global->LDS, 16B per lane. LDS dest is wave-uniform base; HW writes
// lane i at base + i*16. Global src is per-lane.
static __device__ __forceinline__ void gload_lds16(const void* g, void* l) {
    __builtin_amdgcn_global_load_lds(
        (const __attribute__((address_space(1))) unsigned int*)g,
        (__attribute__((address_space(3))) unsigned int*)l, 16, 0, 0);
}

// 4-element vector load -> float4, overloaded on source dtype.
static __device__ __forceinline__ float4 load4(const float* p) {
    return *reinterpret_cast<const float4*>(p);
}
static __device__ __forceinline__ float4 load4(const unsigned short* p) {
    ushort4 v = *reinterpret_cast<const ushort4*>(p);
    return make_float4(bf2f(v.x), bf2f(v.y), bf2f(v.z), bf2f(v.w));
}

// Scalar store, overloaded on destination dtype (fp32 or bf16-bits).
static __device__ __forceinline__ void store1(float* p, float v) { *p = v; }
static __device__ __forceinline__ void store1(unsigned short* p, float v) {
    *p = f2bf(v);
}

// ---------------------------------------------------------------------------
// Fallback fp32 GEMM (used only if workspace is too small for the bf16 path).
// ---------------------------------------------------------------------------
#define BM 128
#define BN 128
#define BK 16
#define LPAD 4

template <typename TA, typename TB, typename TC>
__global__ __launch_bounds__(256) void gemm_f32acc(
    const TA* __restrict__ A,
    const TB* __restrict__ B,
    TC* __restrict__ C,
    int M, int N, int K)
{
    __shared__ float As[BK][BM + LPAD];
    __shared__ float Bs[BK][BN + LPAD];

    const int tid = threadIdx.x;
    const int bm  = blockIdx.y * BM;
    const int bn  = blockIdx.x * BN;
    const int tx  = tid & 15;
    const int ty  = tid >> 4;

    float acc[8][8];
#pragma unroll
    for (int i = 0; i < 8; ++i)
#pragma unroll
        for (int j = 0; j < 8; ++j) acc[i][j] = 0.0f;

    for (int k0 = 0; k0 < K; k0 += BK) {
        for (int q = tid; q < (BM * BK) / 4; q += 256) {
            int row = q >> 2;
            int kq  = (q & 3) << 2;
            float4 v = load4(&A[(size_t)(bm + row) * K + k0 + kq]);
            As[kq + 0][row] = v.x;
            As[kq + 1][row] = v.y;
            As[kq + 2][row] = v.z;
            As[kq + 3][row] = v.w;
        }
        for (int q = tid; q < (BK * BN) / 4; q += 256) {
            int k = q >> 5;
            int n = (q & 31) << 2;
            float4 v = load4(&B[(size_t)(k0 + k) * N + bn + n]);
            Bs[k][n + 0] = v.x;
            Bs[k][n + 1] = v.y;
            Bs[k][n + 2] = v.z;
            Bs[k][n + 3] = v.w;
        }
        __syncthreads();

#pragma unroll
        for (int k = 0; k < BK; ++k) {
            float a[8], b[8];
#pragma unroll
            for (int i = 0; i < 8; ++i) a[i] = As[k][ty * 8 + i];
#pragma unroll
            for (int j = 0; j < 8; ++j) b[j] = Bs[k][tx * 8 + j];
#pragma unroll
            for (int i = 0; i < 8; ++i)
#pragma unroll
                for (int j = 0; j < 8; ++j) acc[i][j] += a[i] * b[j];
        }
        __syncthreads();
    }

#pragma unroll
    for (int i = 0; i < 8; ++i) {
        size_t r = (size_t)(bm + ty * 8 + i);
#pragma unroll
        for (int j = 0; j < 8; ++j) {
            int c = bn + tx * 8 + j;
            store1(&C[r * N + c], acc[i][j]);
        }
    }
}

// ---------------------------------------------------------------------------
// fp32 -> bf16 elementwise convert (vectorized, grid-stride).
// ---------------------------------------------------------------------------
__global__ __launch_bounds__(256) void cvt_f32_bf16(
    const float4* __restrict__ src, ushort4* __restrict__ dst, int n4)
{
    int i = blockIdx.x * 256 + threadIdx.x;
    int stride = gridDim.x * 256;
    for (; i < n4; i += stride) {
        float4 v = src[i];
        dst[i] = make_ushort4(f2bf(v.x), f2bf(v.y), f2bf(v.z), f2bf(v.w));
    }
}

// ---------------------------------------------------------------------------
// fp32 [R][C] -> bf16 [C][R] transpose-convert, 32x32 LDS tiles.
// ---------------------------------------------------------------------------
__global__ __launch_bounds__(256) void transpose_f32_bf16(
    const float* __restrict__ src, unsigned short* __restrict__ dst,
    int R, int C)
{
    __shared__ unsigned short tile[32][33];
    const int r0 = blockIdx.y * 32;
    const int c0 = blockIdx.x * 32;
    const int t  = threadIdx.x;
    const int lr  = t >> 3;          // 0..31
    const int lc4 = (t & 7) << 2;    // 0,4,..,28

    float4 v = load4(&src[(size_t)(r0 + lr) * C + c0 + lc4]);
    tile[lr][lc4 + 0] = f2bf(v.x);
    tile[lr][lc4 + 1] = f2bf(v.y);
    tile[lr][lc4 + 2] = f2bf(v.z);
    tile[lr][lc4 + 3] = f2bf(v.w);
    __syncthreads();

    ushort4 o = make_ushort4(tile[lc4 + 0][lr], tile[lc4 + 1][lr],
                             tile[lc4 + 2][lr], tile[lc4 + 3][lr]);
    *reinterpret_cast<ushort4*>(&dst[(size_t)(c0 + lr) * R + r0 + lc4]) = o;
}

// ---------------------------------------------------------------------------
// MFMA bf16 GEMM (m97 structure): C[M,N] = A[M,K] @ BT[N,K]^T, fp32 accum.
// ---------------------------------------------------------------------------
template <typename TC>
__global__ __launch_bounds__(256) void gemm_bf16_bt(
    const unsigned short* __restrict__ A,    // [M][K] bf16 bits
    const unsigned short* __restrict__ BT,   // [N][K] bf16 bits
    TC* __restrict__ C,                      // [M][N]
    int M, int N, int K)
{
    __shared__ unsigned short As[128 * 32];  // 8 KB
    __shared__ unsigned short Bs[128 * 32];  // 8 KB

    const int tid  = threadIdx.x;
    const int lane = tid & 63;
    const int w    = tid >> 6;
    const int wr   = w >> 1;
    const int wc   = w & 1;
    const int l15  = lane & 15;
    const int l4   = lane >> 4;
    const size_t bm = (size_t)blockIdx.y * 128;
    const size_t bn = (size_t)blockIdx.x * 128;

    f32x4 acc[4][4];
#pragma unroll
    for (int mi = 0; mi < 4; ++mi)
#pragma unroll
        for (int ni = 0; ni < 4; ++ni) acc[mi][ni] = (f32x4){0.f, 0.f, 0.f, 0.f};

    for (int k0 = 0; k0 < K; k0 += 32) {
        __syncthreads();
#pragma unroll
        for (int it = 0; it < 2; ++it) {
            const int cb = (w * 2 + it) * 64;
            const int c  = cb + lane;
            gload_lds16(A  + (bm + (c >> 2)) * K + k0 + (c & 3) * 8,
                        (char*)As + cb * 16);
            gload_lds16(BT + (bn + (c >> 2)) * K + k0 + (c & 3) * 8,
                        (char*)Bs + cb * 16);
        }
        __syncthreads();

        bf16x8 a[4], b[4];
#pragma unroll
        for (int mi = 0; mi < 4; ++mi)
            a[mi] = *reinterpret_cast<const bf16x8*>(
                (char*)As + (wr * 64 + mi * 16 + l15) * 64 + l4 * 16);
#pragma unroll
        for (int ni = 0; ni < 4; ++ni)
            b[ni] = *reinterpret_cast<const bf16x8*>(
                (char*)Bs + (wc * 64 + ni * 16 + l15) * 64 + l4 * 16);
#pragma unroll
        for (int mi = 0; mi < 4; ++mi)
#pragma unroll
            for (int ni = 0; ni < 4; ++ni)
                acc[mi][ni] = __builtin_amdgcn_mfma_f32_16x16x32_bf16(
                    a[mi], b[ni], acc[mi][ni], 0, 0, 0);
    }

#pragma unroll
    for (int mi = 0; mi < 4; ++mi) {
#pragma unroll
        for (int r = 0; r < 4; ++r) {
            size_t row = bm + wr * 64 + mi * 16 + l4 * 4 + r;
#pragma unroll
            for (int ni = 0; ni < 4; ++ni) {
                size_t col = bn + wc * 64 + ni * 16 + l15;
                store1(&C[row * N + col], acc[mi][ni][r]);
            }
        }
    }
}

// ---------------------------------------------------------------------------
// RoPE applied in place to the Q and K regions of qkv (S x 6144, bf16).
// ---------------------------------------------------------------------------
__global__ __launch_bounds__(256) void rope_kernel(
    unsigned short* __restrict__ qkv,
    const int* __restrict__ pos32,
    int S)
{
    int idx = blockIdx.x * 256 + threadIdx.x;
    int total = S * (NQ + NKV) * (HD / 2);
    if (idx >= total) return;

    int j    = idx & 63;
    int head = (idx >> 6) % (NQ + NKV);
    int s    = idx / (64 * (NQ + NKV));

    const bool is64 = (pos32[1] == 0);      // int64 little-endian arange
    int pos = is64 ? pos32[2 * s] : pos32[s];

    unsigned short* row = qkv + (size_t)s * NQKV + head * HD;
    float x1 = bf2f(row[j]);
    float x2 = bf2f(row[j + 64]);

    float p = (float)pos;
    float inv_freq = powf(10000.0f, -((float)j) * (1.0f / 64.0f));
    float f = p * inv_freq;
    float sn, cs;
    sincosf(f, &sn, &cs);

    row[j]      = f2bf(x1 * cs - x2 * sn);
    row[j + 64] = f2bf(x2 * cs + x1 * sn);
}

// ---------------------------------------------------------------------------
// MFMA flash attention v4: v3 structure + single-barrier double-buffered
// pipeline (T3-minimum + T14 async-stage split).
//
// Per tile t: (a) ISSUE next tile's K global_load_lds into Ks[cur^1] and V
// global loads into registers; (b) compute tile t from buf[cur]; (c) scatter
// V regs -> Vts[cur^1] (vmcnt wait lands AFTER ~1000cyc of compute); (d) ONE
// barrier (its implicit vmcnt(0) drain covers the K gloads, which have had
// the whole compute phase to land). Invariant: buf[cur^1] was last read in
// iteration t-1, whose end barrier precedes these writes.
//
//  QK^T : mfma(A=K, B=Q) -> D[m=key][n=qrow]; softmax fully in-register.
//  P->PV: V staged with key rows permuted by slot() so P's natural C-layout
//         regs ARE the PV A-fragments (zero cross-lane exchange).
//  T13  : defer-max (THR=8) skips O-rescale when running max doesn't grow.
// ---------------------------------------------------------------------------
__global__ __launch_bounds__(256, 2) void attn_mfma(
    const unsigned short* __restrict__ qkv,   // S x 6144 bf16 bits (RoPE'd)
    unsigned short* __restrict__ attn_out,    // S x 4096 bf16 bits
    int S)
{
    __shared__ unsigned short Ks[2][64 * 128];    // 2 x 16 KB (rows 256B, swz)
    __shared__ unsigned short Vts[2][128 * 64];   // 2 x 16 KB (V^T, slot-perm)

    const int tid  = threadIdx.x;
    const int lane = tid & 63;
    const int w    = tid >> 6;        // wave 0..3
    const int l15  = lane & 15;
    const int l4   = lane >> 4;       // quarter 0..3
    const int h    = blockIdx.y;      // query head
    const int g    = h >> 2;          // kv head
    const int xb   = (int)gridDim.x - 1 - (int)blockIdx.x;  // heavy-first
    const int s0   = xb * 128;
    const int qw   = s0 + w * 32;     // wave q range

    // Q B-fragments, pre-scaled: qf[qt][ks] -> Q[qw+qt*16+l15][ks*32+l4*8 ..]
    bf16x8 qf[2][4];
#pragma unroll
    for (int qt = 0; qt < 2; ++qt) {
        const unsigned short* qrow =
            qkv + (size_t)(qw + qt * 16 + l15) * NQKV + h * HD;
#pragma unroll
        for (int ks = 0; ks < 4; ++ks) {
            bf16x8 v = *reinterpret_cast<const bf16x8*>(qrow + ks * 32 + l4 * 8);
            bf16x8 o;
#pragma unroll
            for (int i = 0; i < 8; ++i)
                o[i] = (short)f2bf(bf2f((unsigned short)v[i]) * SCALE);
            qf[qt][ks] = o;
        }
    }

    f32x4 oacc[2][8];
#pragma unroll
    for (int qt = 0; qt < 2; ++qt)
#pragma unroll
        for (int dt = 0; dt < 8; ++dt) oacc[qt][dt] = (f32x4){0.f, 0.f, 0.f, 0.f};
    float m_r[2] = {-1e30f, -1e30f};   // running max for qrow qt*16+l15
    float l_r[2] = {0.f, 0.f};

    const int nt_max = 2 * xb + 2;
    const int nt_w   = 2 * xb + 1 + (w >> 1);   // waves 0,1 need one tile less

    // V staging registers (per-thread element cc = tid + it*256:
    // key = cc&63, d0 = (cc>>6)*8).
    bf16x8 vreg[4];

    // ---- staging helpers ----
    auto stage_K = [&](int t0, unsigned short* Kbuf) {
#pragma unroll
        for (int it = 0; it < 4; ++it) {
            const int seg  = it * 4 + w;          // 16 segments of 64 chunks
            const int clin = seg * 64 + lane;
            const int key  = clin >> 4;
            const int csrc = (clin & 15) ^ (key & 7);   // pre-swizzled source
            gload_lds16(qkv + (size_t)(t0 + key) * NQKV + KOFF + g * HD + csrc * 8,
                        (char*)Kbuf + (size_t)seg * 1024);
        }
    };
    auto load_V = [&](int t0) {
#pragma unroll
        for (int it = 0; it < 4; ++it) {
            const int cc  = tid + it * 256;
            const int key = cc & 63;
            const int d0  = (cc >> 6) * 8;
            vreg[it] = *reinterpret_cast<const bf16x8*>(
                qkv + (size_t)(t0 + key) * NQKV + VOFF + g * HD + d0);
        }
    };
    auto scatter_V = [&](unsigned short* Vbuf) {
#pragma unroll
        for (int it = 0; it < 4; ++it) {
            const int cc  = tid + it * 256;
            const int key = cc & 63;
            const int d0  = (cc >> 6) * 8;
            const int kt   = key >> 4;
            const int slot = 32 * (kt >> 1) + 8 * ((key >> 2) & 3) +
                             4 * (kt & 1) + (key & 3);
#pragma unroll
            for (int j = 0; j < 8; ++j) {
                const int d = d0 + j;
                *reinterpret_cast<unsigned short*>(
                    (char*)Vbuf + d * 128 + (((slot >> 3) ^ (d & 7)) << 4) +
                    (slot & 7) * 2) = (unsigned short)vreg[it][j];
            }
        }
    };

    // ---- prologue: stage tile 0 into buffer 0 ----
    stage_K(0, Ks[0]);
    load_V(0);
    scatter_V(Vts[0]);
    __syncthreads();   // implicit vmcnt(0) drain covers the K gloads

    for (int t = 0; t < nt_max; ++t) {
        const int cur = t & 1;
        const bool pre = (t + 1 < nt_max);

        // (a) issue next tile's staging loads (before compute)
        if (pre) {
            stage_K((t + 1) * 64, Ks[cur ^ 1]);
            load_V((t + 1) * 64);
        }

        // (b) compute tile t from buf[cur]
        if (t < nt_w) {
            const int t0 = t * 64;

            // QK^T: D[key][qrow], A=K-frag from LDS, B=Q regs
            f32x4 sacc[4][2];
#pragma unroll
            for (int kt = 0; kt < 4; ++kt) {
                sacc[kt][0] = (f32x4){0.f, 0.f, 0.f, 0.f};
                sacc[kt][1] = (f32x4){0.f, 0.f, 0.f, 0.f};
            }
#pragma unroll
            for (int kt = 0; kt < 4; ++kt) {
                const int key = kt * 16 + l15;
                const char* krow = (const char*)Ks[cur] + key * 256;
                const int swz = key & 7;
#pragma unroll
                for (int ks = 0; ks < 4; ++ks) {
                    bf16x8 kb = *reinterpret_cast<const bf16x8*>(
                        krow + (((ks * 4 + l4) ^ swz) << 4));
                    sacc[kt][0] = __builtin_amdgcn_mfma_f32_16x16x32_bf16(
                        kb, qf[0][ks], sacc[kt][0], 0, 0, 0);
                    sacc[kt][1] = __builtin_amdgcn_mfma_f32_16x16x32_bf16(
                        kb, qf[1][ks], sacc[kt][1], 0, 0, 0);
                }
            }

            // causal mask (wave's diagonal tile only)
            if (t == nt_w - 1) {
#pragma unroll
                for (int kt = 0; kt < 4; ++kt) {
                    const int keyb = t0 + kt * 16 + l4 * 4;
#pragma unroll
                    for (int qt = 0; qt < 2; ++qt) {
                        const int qrow = qw + qt * 16 + l15;
#pragma unroll
                        for (int r = 0; r < 4; ++r)
                            if (keyb + r > qrow) sacc[kt][qt][r] = -1e30f;
                    }
                }
            }

            // in-register online softmax (defer-max, THR=8)
            float pmax[2];
#pragma unroll
            for (int qt = 0; qt < 2; ++qt) {
                float mx = sacc[0][qt][0];
#pragma unroll
                for (int kt = 0; kt < 4; ++kt)
#pragma unroll
                    for (int r = 0; r < 4; ++r) mx = fmaxf(mx, sacc[kt][qt][r]);
                mx = fmaxf(mx, __shfl_xor(mx, 16));
                mx = fmaxf(mx, __shfl_xor(mx, 32));
                pmax[qt] = mx;
            }
            const bool need = (pmax[0] > m_r[0] + 8.f) ||
                              (pmax[1] > m_r[1] + 8.f);
            if (__any(need)) {   // rare rescale path
#pragma unroll
                for (int qt = 0; qt < 2; ++qt) {
                    float mnew  = fmaxf(m_r[qt], pmax[qt]);
                    float alpha = __expf(m_r[qt] - mnew);
                    l_r[qt] *= alpha;
                    m_r[qt]  = mnew;
#pragma unroll
                    for (int r = 0; r < 4; ++r) {
                        float ar = __shfl(alpha, l4 * 4 + r);
#pragma unroll
                        for (int dt = 0; dt < 8; ++dt) oacc[qt][dt][r] *= ar;
                    }
                }
            }

            // P = exp(s - m), packed directly as PV A-fragments (slot order)
            bf16x8 pa[2][2];   // [qt][ks2]; elem j = 4*(kt&1)+r, ks2 = kt>>1
#pragma unroll
            for (int qt = 0; qt < 2; ++qt) {
                float lsum = 0.f;
#pragma unroll
                for (int kt = 0; kt < 4; ++kt) {
#pragma unroll
                    for (int r = 0; r < 4; ++r) {
                        float p = __expf(sacc[kt][qt][r] - m_r[qt]);
                        lsum += p;
                        pa[qt][kt >> 1][4 * (kt & 1) + r] = (short)f2bf(p);
                    }
                }
                lsum += __shfl_xor(lsum, 16);
                lsum += __shfl_xor(lsum, 32);
                l_r[qt] += lsum;
            }

            // PV: O[qrow][d] += P @ Vperm
#pragma unroll
            for (int dt = 0; dt < 8; ++dt) {
                const int d = dt * 16 + l15;
                const char* vrow = (const char*)Vts[cur] + d * 128;
                const int swz = d & 7;
#pragma unroll
                for (int ks2 = 0; ks2 < 2; ++ks2) {
                    bf16x8 vb = *reinterpret_cast<const bf16x8*>(
                        vrow + (((ks2 * 4 + l4) ^ swz) << 4));
                    oacc[0][dt] = __builtin_amdgcn_mfma_f32_16x16x32_bf16(
                        pa[0][ks2], vb, oacc[0][dt], 0, 0, 0);
                    oacc[1][dt] = __builtin_amdgcn_mfma_f32_16x16x32_bf16(
                        pa[1][ks2], vb, oacc[1][dt], 0, 0, 0);
                }
            }
        }

        // (c) write-late: V regs -> Vts[cur^1] (vmcnt wait after compute)
        if (pre) scatter_V(Vts[cur ^ 1]);

        // (d) single barrier: syncs buf swap AND drains K gloads (vmcnt(0))
        __syncthreads();
    }

    // ---- epilogue: normalize rows (O row = qt*16 + l4*4 + r), store bf16 ----
#pragma unroll
    for (int qt = 0; qt < 2; ++qt) {
        float linv_own = 1.0f / l_r[qt];
#pragma unroll
        for (int r = 0; r < 4; ++r) {
            float linv = __shfl(linv_own, l4 * 4 + r);
            const int row = qw + qt * 16 + l4 * 4 + r;
            unsigned short* dst = attn_out + (size_t)row * (NQ * HD) + h * HD;
#pragma unroll
            for (int dt = 0; dt < 8; ++dt)
                dst[dt * 16 + l15] = f2bf(oacc[qt][dt][r] * linv);
        }
    }
}

// ---------------------------------------------------------------------------
extern "C" void kernel_launch(void* const* d_in, const int* in_sizes, int n_in,
                              void* d_out, int out_size, void* d_ws, size_t ws_size,
                              hipStream_t stream)
{
    const int*   positions = (const int*)d_in[0];     // int32/int64 (detected)
    const float* hidden    = (const float*)d_in[1];   // S x 4096 fp32
    const float* w_qkv     = (const float*)d_in[2];   // 4096 x 6144 fp32
    const float* w_o       = (const float*)d_in[3];   // 4096 x 4096 fp32
    const int S = in_sizes[0];
    const size_t Sz = (size_t)S;

    // Workspace layout (bf16 halves)
    unsigned short* qkv   = (unsigned short*)d_ws;
    unsigned short* attn  = qkv   + Sz * NQKV;
    unsigned short* hbf   = attn  + Sz * H_DIM;
    unsigned short* wqkvT = hbf   + Sz * H_DIM;
    unsigned short* woT   = wqkvT + (size_t)NQKV * H_DIM;
    const size_t need = (Sz * NQKV + Sz * H_DIM + Sz * H_DIM +
                         (size_t)NQKV * H_DIM + (size_t)H_DIM * H_DIM) *
                        sizeof(unsigned short);

    if (ws_size >= need) {
        // 0a) hidden -> bf16
        int n4 = (S * H_DIM) / 4;
        int cg = (n4 + 255) / 256; if (cg > 2048) cg = 2048;
        cvt_f32_bf16<<<cg, 256, 0, stream>>>(
            (const float4*)hidden, (ushort4*)hbf, n4);
        // 0b) w_qkv [4096][6144] -> wqkvT [6144][4096] bf16
        transpose_f32_bf16<<<dim3(NQKV / 32, H_DIM / 32), 256, 0, stream>>>(
            w_qkv, wqkvT, H_DIM, NQKV);
        // 0c) w_o [4096][4096] -> woT bf16
        transpose_f32_bf16<<<dim3(H_DIM / 32, H_DIM / 32), 256, 0, stream>>>(
            w_o, woT, H_DIM, H_DIM);

        // 1) QKV projection (bf16 MFMA, fp32 accum)
        gemm_bf16_bt<unsigned short><<<dim3(NQKV / 128, S / 128), 256, 0, stream>>>(
            hbf, wqkvT, qkv, S, NQKV, H_DIM);

        // 2) RoPE on Q and K regions (in place, bf16)
        int total = S * (NQ + NKV) * (HD / 2);
        rope_kernel<<<(total + 255) / 256, 256, 0, stream>>>(qkv, positions, S);

        // 3) Causal GQA flash attention v4 (bf16 -> bf16 ws)
        attn_mfma<<<dim3(S / 128, NQ), 256, 0, stream>>>(qkv, attn, S);

        // 4) Output projection -> d_out (fp32)
        gemm_bf16_bt<float><<<dim3(H_DIM / 128, S / 128), 256, 0, stream>>>(
            attn, woT, (float*)d_out, S, H_DIM, H_DIM);
    } else {
        // --- fallback: fp32-GEMM path (80 MB workspace) ---
        gemm_f32acc<float, float, unsigned short>
            <<<dim3(NQKV / BN, S / BM), 256, 0, stream>>>(
                hidden, w_qkv, qkv, S, NQKV, H_DIM);
        int total = S * (NQ + NKV) * (HD / 2);
        rope_kernel<<<(total + 255) / 256, 256, 0, stream>>>(qkv, positions, S);
        attn_mfma<<<dim3(S / 128, NQ), 256, 0, stream>>>(qkv, attn, S);
        gemm_f32acc<unsigned short, float, float>
            <<<dim3(H_DIM / BN, S / BM), 256, 0, stream>>>(
                attn, w_o, (float*)d_out, S, H_DIM, H_DIM);
    }
}